// Round 1
// 174.311 us; speedup vs baseline: 1.2563x; 1.2563x over previous
//
#include <hip/hip_runtime.h>
#include <stdint.h>

#define NB 8
#define NPRED 25200
#define NTOP 1000
#define NCLS 80
#define CONF_T 0.25f
#define IOU_THR 0.45f
#define MAXWH 4096.0f
#define CAP 2048
#define NBINS 1025
#define SBLK 128
#define SBPB 197   // ceil(25200/128): 197*128 = 25216

typedef unsigned long long u64;

// ---------------------------------------------------------------------------
// K1: score/class per pred + global histogram of score bits.
// Staging via global_load_lds width=16 (no VGPR round trip).
// ---------------------------------------------------------------------------
__global__ __launch_bounds__(128) void k_score(const float* __restrict__ x,
                                               float* __restrict__ msc,
                                               int* __restrict__ cls,
                                               unsigned* __restrict__ hist) {
#pragma clang fp contract(off)
    __shared__ __align__(16) float sm[SBLK * 85];
    const int b = blockIdx.x / SBPB;
    const int blk = blockIdx.x % SBPB;
    const int t = threadIdx.x;
    const int wave = t >> 6, lane = t & 63;
    const long long TOT4 = (long long)NB * NPRED * 85 / 4;  // 4,284,000
    const long long base4 = ((long long)b * NPRED + (long long)blk * SBLK) * 85 / 4;
    const float4* x4 = (const float4*)x;
    const int tile4 = SBLK * 85 / 4;  // 2720

    for (int k = 0; k < 22; ++k) {
        int ib = k * 128 + wave * 64;      // wave-uniform lds base (float4 units)
        int fi = ib + lane;
        if (fi < tile4) {
            long long gi = base4 + fi;
            if (gi >= TOT4) gi = TOT4 - 1;  // tail clamp (outputs guarded below)
            __builtin_amdgcn_global_load_lds(
                (const __attribute__((address_space(1))) void*)(x4 + gi),
                (__attribute__((address_space(3))) void*)(sm + (size_t)ib * 4),
                16, 0, 0);
        }
    }
    __syncthreads();

    int pred = blk * SBLK + t;
    if (pred < NPRED) {
        const float* p = &sm[t * 85];
        float obj = p[4];
        float best = p[5];
        int bid = 0;
        for (int c = 1; c < NCLS; ++c) {
            float v = p[5 + c];
            if (v > best) { best = v; bid = c; }  // strict >: first occurrence
        }
        float score = obj * best;
        int q = b * NPRED + pred;
        msc[q] = (score > CONF_T) ? score : -1.0f;
        cls[q] = bid;
        if (score > CONF_T) {
            int bin = (int)(__float_as_uint(score) >> 14) - 0xFA00;
            bin = bin < 0 ? 0 : (bin > 1024 ? 1024 : bin);
            atomicAdd(&hist[b * NBINS + bin], 1u);
        }
    }
}

// ---------------------------------------------------------------------------
// K2 (fused): per-batch boundary-bin + compact-into-LDS + bitonic sort of
// <=2048 candidates (1024 threads) + gather top-1000.
// Key = (~score_bits << 32) | idx : ascending sort = descending score,
// ascending index on ties (stable top_k semantics).
// ---------------------------------------------------------------------------
__global__ __launch_bounds__(1024) void k_sort(const float* __restrict__ x,
                                               const float* __restrict__ msc,
                                               const int* __restrict__ cls,
                                               const unsigned* __restrict__ hist,
                                               float* __restrict__ det,
                                               float* __restrict__ offb,
                                               unsigned* __restrict__ valid) {
#pragma clang fp contract(off)
    __shared__ u64 keys[CAP];
    __shared__ int sB;
    __shared__ unsigned lcnt;
    const int b = blockIdx.x, t = threadIdx.x;
    const float* ms = msc + (size_t)b * NPRED;

    if (t == 0) lcnt = 0;
    if (t < 64) {  // wave 0: suffix-count boundary bin B
        const int lane = t;
        const unsigned* h = hist + b * NBINS;
        const int hi2 = 1024 - 16 * lane;       // lane chunk: bins [hi2-15, hi2]
        unsigned sum = 0;
        for (int k = 0; k < 16; ++k) sum += h[hi2 - k];
        if (lane == 63) sum += h[0];
        unsigned v = sum;
        for (int d = 1; d < 64; d <<= 1) {
            unsigned o = __shfl_up(v, d);
            if (lane >= d) v += o;
        }
        unsigned excl = v - sum;                // count strictly above my chunk
        u64 ball = __ballot(v >= NTOP);
        int B = 0;
        if (ball != 0) {
            int sel = __builtin_ctzll(ball);
            if (lane == sel) {
                unsigned run = excl;
                for (int k = 0; k < 16; ++k) {
                    run += h[hi2 - k];
                    if (run >= NTOP) { B = hi2 - k; break; }
                }
            }
            B = __shfl(B, sel);
        }
        if (lane == 0) sB = B;
    }
    __syncthreads();
    const int B = sB;

    // compact candidates (bin >= B) into LDS
    for (int p = t; p < NPRED; p += 1024) {
        float s = ms[p];
        if (s > CONF_T) {
            unsigned bits = __float_as_uint(s);
            int bin = (int)(bits >> 14) - 0xFA00;
            bin = bin < 0 ? 0 : (bin > 1024 ? 1024 : bin);
            if (bin >= B) {
                unsigned slot = atomicAdd(&lcnt, 1u);
                if (slot < CAP)
                    keys[slot] = ((u64)(~bits) << 32) | (unsigned)p;
            }
        }
    }
    __syncthreads();
    unsigned c = lcnt; if (c > CAP) c = CAP;
    for (int i = (int)c + t; i < CAP; i += 1024) keys[i] = ~0ULL;
    __syncthreads();

    // bitonic sort CAP keys ascending; 1 compare-exchange per thread per round
    for (unsigned k = 2; k <= CAP; k <<= 1) {
        for (unsigned j = k >> 1; j > 0; j >>= 1) {
            unsigned i = (((unsigned)t & ~(j - 1)) << 1) | ((unsigned)t & (j - 1));
            unsigned pi = i | j;
            bool up = ((i & k) == 0);
            u64 a = keys[i], d = keys[pi];
            bool sw = up ? (a > d) : (a < d);
            if (sw) { keys[i] = d; keys[pi] = a; }
            __syncthreads();
        }
    }

    // gather top-1000 -> det rows, class-offset boxes, valid flags
    if (t < NTOP) {
        u64 key = keys[t];
        unsigned p = (unsigned)key;
        float score = __uint_as_float(~(unsigned)(key >> 32));
        bool v = score > CONF_T;
        float o0 = 0, o1 = 0, o2 = 0, o3 = 0, o4 = 0, o5 = 0;
        float f0 = 0, f1 = 0, f2 = 0, f3 = 0;
        if (v) {
            const float* xp = x + ((size_t)b * NPRED + p) * 85;
            float xc = xp[0], yc = xp[1], w = xp[2], h = xp[3];
            float hw = w * 0.5f, hh = h * 0.5f;
            o0 = xc - hw; o1 = yc - hh; o2 = xc + hw; o3 = yc + hh;
            o4 = score;
            float cf = (float)cls[(size_t)b * NPRED + p];
            o5 = cf;
            float co = cf * MAXWH;
            f0 = o0 + co; f1 = o1 + co; f2 = o2 + co; f3 = o3 + co;
        }
        size_t d6 = ((size_t)b * NTOP + t) * 6;
        det[d6 + 0] = o0; det[d6 + 1] = o1; det[d6 + 2] = o2;
        det[d6 + 3] = o3; det[d6 + 4] = o4; det[d6 + 5] = o5;
        size_t d4 = ((size_t)b * NTOP + t) * 4;
        offb[d4 + 0] = f0; offb[d4 + 1] = f1; offb[d4 + 2] = f2; offb[d4 + 3] = f3;
        valid[(size_t)b * NTOP + t] = v ? 1u : 0u;
    }
}

// ---------------------------------------------------------------------------
// K3: 1000x1000 IoU bitmask. Lanes <-> consecutive rows; columns are
// broadcast LDS reads (conflict-free). grid = 8 batches x 32 row-groups.
// ---------------------------------------------------------------------------
__global__ __launch_bounds__(256) void k_iou(const float* __restrict__ offb,
                                             u64* __restrict__ mask) {
#pragma clang fp contract(off)
    __shared__ __align__(16) float4 bx4[NTOP];
    __shared__ float area[NTOP];
    const int b = blockIdx.x >> 5;
    const int rg = blockIdx.x & 31;
    const float4* ob = (const float4*)(offb + (size_t)b * NTOP * 4);
    for (int i = threadIdx.x; i < NTOP; i += 256) {
        float4 v = ob[i];
        bx4[i] = v;
        area[i] = (v.z - v.x) * (v.w - v.y);
    }
    __syncthreads();
    const int i = rg * 32 + (threadIdx.x & 31);
    const int q = threadIdx.x >> 5;            // 8 word-pairs
    if (i >= NTOP) return;
    float4 A = bx4[i];
    float areaA = area[i];
    u64* mrow = &mask[((size_t)b * NTOP + i) * 16];
    for (int wi = 0; wi < 2; ++wi) {
        int w = q * 2 + wi;
        u64 bits = 0;
        int c0 = w * 64;
        for (int cc = 0; cc < 64; ++cc) {
            int col = c0 + cc;
            if (col >= NTOP) break;
            float4 Bb = bx4[col];              // broadcast read
            float ltx = fmaxf(A.x, Bb.x), lty = fmaxf(A.y, Bb.y);
            float rbx = fminf(A.z, Bb.z), rby = fminf(A.w, Bb.w);
            float ww = fmaxf(rbx - ltx, 0.0f), hh = fmaxf(rby - lty, 0.0f);
            float inter = ww * hh;
            float iou = inter / (((areaA + area[col]) - inter) + 1e-9f);
            if (iou > IOU_THR && col != i) bits |= (1ULL << cc);
        }
        mrow[w] = bits;
    }
}

// ---------------------------------------------------------------------------
// K4: greedy scan, one wave per batch. Event-driven scalar formulation:
// the serial recurrence only advances at KEPT rows whose intra-group
// (64x64 diagonal-block) mask word is nonzero. Reduce incoming suppression
// to an SGPR (readfirstlane), ballot the nonzero-row set, then loop ONLY
// over events (ctz-ordered). Zero-row bits are finalized in bulk with
// kb |= vb & ~S. Bit-exact greedy semantics: any valid, unsuppressed,
// nonzero-row bit below the current event would itself be the minimum
// event, so bulk finalization below each event is safe; S grows
// monotonically and kb is OR-accumulated so re-finalization is idempotent.
// Worst (dense) case degrades to <=64 scalar iterations per group.
// Replaces the previous fully-unrolled 1024-step readlane chain (~115 KB
// straight-line code -> icache streaming + spill traffic at 1 wave/CU).
// ---------------------------------------------------------------------------
__device__ __forceinline__ u64 shfl_xor_u64(u64 v, int m) {
    int lo = __shfl_xor((int)(unsigned)v, m);
    int hi = __shfl_xor((int)(unsigned)(v >> 32), m);
    return ((u64)(unsigned)hi << 32) | (unsigned)lo;
}

__global__ __launch_bounds__(64) void k_scan(const u64* __restrict__ mask,
                                             const unsigned* __restrict__ valid,
                                             const float* __restrict__ det,
                                             float* __restrict__ out) {
    const int b = blockIdx.x;
    const int lane = threadIdx.x;
    const u64* mb = mask + (size_t)b * NTOP * 16;
    u64 acc[16];
    u64 buf[3][16];
#pragma unroll
    for (int w = 0; w < 16; ++w) acc[w] = 0;

    u64 vbs[16];
#pragma unroll
    for (int g = 0; g < 16; ++g) {
        int r = g * 64 + lane;
        unsigned vf = (r < NTOP) ? valid[(size_t)b * NTOP + r] : 0u;
        vbs[g] = __ballot(vf != 0);   // wave-uniform -> SGPRs
    }

    auto loadgrp = [&](int g, u64* dst) {
        int r = g * 64 + lane;
        if (r < NTOP) {
            const u64* rp = mb + (size_t)r * 16;
#pragma unroll
            for (int w = 0; w < 16; ++w) dst[w] = rp[w];
        } else {
#pragma unroll
            for (int w = 0; w < 16; ++w) dst[w] = 0;
        }
    };
    loadgrp(0, buf[0]);
    loadgrp(1, buf[1]);

#pragma unroll
    for (int g = 0; g < 16; ++g) {
        if (g + 2 < 16) loadgrp(g + 2, buf[(g + 2) % 3]);
        u64* cur = buf[g % 3];

        // wave-uniform suppression word for this group from prior keeps;
        // butterfly OR-reduce, then pin to SGPRs so the event loop is SALU.
        u64 Sv = acc[g];
        Sv |= shfl_xor_u64(Sv, 1);  Sv |= shfl_xor_u64(Sv, 2);  Sv |= shfl_xor_u64(Sv, 4);
        Sv |= shfl_xor_u64(Sv, 8);  Sv |= shfl_xor_u64(Sv, 16); Sv |= shfl_xor_u64(Sv, 32);
        unsigned slo = (unsigned)__builtin_amdgcn_readfirstlane((int)(unsigned)Sv);
        unsigned shi = (unsigned)__builtin_amdgcn_readfirstlane((int)(unsigned)(Sv >> 32));
        u64 S = ((u64)shi << 32) | slo;

        const u64 vb = vbs[g];
        const u64 nz = __ballot(cur[g] != 0ULL);   // rows with intra-group bits
        const int clo = (int)(unsigned)cur[g];
        const int chi = (int)(unsigned)(cur[g] >> 32);

        u64 kb = 0;
        u64 events = nz & vb & ~S;   // kept-candidates that can change S
        while (events) {
            int t = (int)__builtin_ctzll(events);
            u64 bit = 1ULL << t;
            u64 below = bit - 1;
            kb |= vb & ~S & below;   // finalize zero-row span below this event
            kb |= bit;               // event row is valid & unsuppressed: keep
            unsigned mlo = (unsigned)__builtin_amdgcn_readlane(clo, t);
            unsigned mhi = (unsigned)__builtin_amdgcn_readlane(chi, t);
            S |= ((u64)mhi << 32) | mlo;
            events &= ~bit;
            events &= ~S;
        }
        kb |= vb & ~S;               // finalize remainder under final S

        bool mykeep = (kb >> lane) & 1ULL;
#pragma unroll
        for (int w = 0; w < 16; ++w) acc[w] |= mykeep ? cur[w] : 0ULL;

        int r = g * 64 + lane;          // fused masked output write
        if (r < NTOP) {
            const float* dp = det + ((size_t)b * NTOP + r) * 6;
            float* op = out + ((size_t)b * NTOP + r) * 6;
#pragma unroll
            for (int c2 = 0; c2 < 6; ++c2) {
                float v = dp[c2];
                op[c2] = mykeep ? v : 0.0f;
            }
        }
    }
}

// ---------------------------------------------------------------------------
extern "C" void kernel_launch(void* const* d_in, const int* in_sizes, int n_in,
                              void* d_out, int out_size, void* d_ws, size_t ws_size,
                              hipStream_t stream) {
    const float* x = (const float*)d_in[0];
    char* ws = (char*)d_ws;
    // layout (bytes):
    float* msc = (float*)(ws);                       //       0 .. 806400
    int* cls = (int*)(ws + 806400);                  //  806400 .. 1612800
    float* det = (float*)(ws + 1612800);             // 1612800 .. 1804800
    float* offb = (float*)(ws + 1804800);            // 1804800 .. 1932800
    unsigned* valid = (unsigned*)(ws + 1932800);     // 1932800 .. 1964800
    u64* mask = (u64*)(ws + 1964800);                // 1964800 .. 2988800
    // hist overlays the mask region (consumed by k_sort before k_iou writes):
    unsigned* hist = (unsigned*)(ws + 1964800);      // 8*1025*4 = 32800

    hipMemsetAsync(hist, 0, 32800, stream);
    k_score<<<NB * SBPB, 128, 0, stream>>>(x, msc, cls, hist);
    k_sort<<<NB, 1024, 0, stream>>>(x, msc, cls, hist, det, offb, valid);
    k_iou<<<NB * 32, 256, 0, stream>>>(offb, mask);
    k_scan<<<NB, 64, 0, stream>>>(mask, valid, det, (float*)d_out);
}

// Round 2
// 173.688 us; speedup vs baseline: 1.2608x; 1.0036x over previous
//
#include <hip/hip_runtime.h>
#include <stdint.h>

#define NB 8
#define NPRED 25200
#define NTOP 1000
#define NCLS 80
#define CONF_T 0.25f
#define IOU_THR 0.45f
#define MAXWH 4096.0f
#define CAP 2048
#define NBINS 1025
#define SBLK 128
#define SBPB 197   // ceil(25200/128): 197*128 = 25216

typedef unsigned long long u64;

__device__ __forceinline__ u64 shfl_xor_u64(u64 v, int m) {
    int lo = __shfl_xor((int)(unsigned)v, m);
    int hi = __shfl_xor((int)(unsigned)(v >> 32), m);
    return ((u64)(unsigned)hi << 32) | (unsigned)lo;
}

// ---------------------------------------------------------------------------
// K1: score/class per pred + global histogram of score bits.
// Staging via global_load_lds width=16 (no VGPR round trip).
// ---------------------------------------------------------------------------
__global__ __launch_bounds__(128) void k_score(const float* __restrict__ x,
                                               float* __restrict__ msc,
                                               int* __restrict__ cls,
                                               unsigned* __restrict__ hist) {
#pragma clang fp contract(off)
    __shared__ __align__(16) float sm[SBLK * 85];
    const int b = blockIdx.x / SBPB;
    const int blk = blockIdx.x % SBPB;
    const int t = threadIdx.x;
    const int wave = t >> 6, lane = t & 63;
    const long long TOT4 = (long long)NB * NPRED * 85 / 4;  // 4,284,000
    const long long base4 = ((long long)b * NPRED + (long long)blk * SBLK) * 85 / 4;
    const float4* x4 = (const float4*)x;
    const int tile4 = SBLK * 85 / 4;  // 2720

    for (int k = 0; k < 22; ++k) {
        int ib = k * 128 + wave * 64;      // wave-uniform lds base (float4 units)
        int fi = ib + lane;
        if (fi < tile4) {
            long long gi = base4 + fi;
            if (gi >= TOT4) gi = TOT4 - 1;  // tail clamp (outputs guarded below)
            __builtin_amdgcn_global_load_lds(
                (const __attribute__((address_space(1))) void*)(x4 + gi),
                (__attribute__((address_space(3))) void*)(sm + (size_t)ib * 4),
                16, 0, 0);
        }
    }
    __syncthreads();

    int pred = blk * SBLK + t;
    if (pred < NPRED) {
        const float* p = &sm[t * 85];
        float obj = p[4];
        float best = p[5];
        int bid = 0;
        for (int c = 1; c < NCLS; ++c) {
            float v = p[5 + c];
            if (v > best) { best = v; bid = c; }  // strict >: first occurrence
        }
        float score = obj * best;
        int q = b * NPRED + pred;
        msc[q] = (score > CONF_T) ? score : -1.0f;
        cls[q] = bid;
        if (score > CONF_T) {
            int bin = (int)(__float_as_uint(score) >> 14) - 0xFA00;
            bin = bin < 0 ? 0 : (bin > 1024 ? 1024 : bin);
            atomicAdd(&hist[b * NBINS + bin], 1u);
        }
    }
}

// ---------------------------------------------------------------------------
// K2 (fused): per-batch boundary-bin + compact-into-LDS + bitonic sort of
// <=2048 candidates (1024 threads) + gather top-1000.
// Key = (~score_bits << 32) | idx : ascending sort = descending score,
// ascending index on ties (stable top_k semantics).
// Bitonic is hybrid: j>=64 levels in LDS (consecutive-lane u64 access =
// 2 lanes/bank, conflict-free); all j<=32 levels run in registers via
// __shfl_xor (each wave owns elements w*128+l and w*128+64+l, and for
// j<=32 the CE partner i^j stays inside the same 64-aligned segment =
// same wave). k=2..64 fuse into ONE register phase (no barriers).
// Replaces 66 barrier rounds (51 of them 8-way bank-conflicted at 16B
// stride) with 15 conflict-free LDS rounds + 12 register phases.
// ---------------------------------------------------------------------------
__global__ __launch_bounds__(1024) void k_sort(const float* __restrict__ x,
                                               const float* __restrict__ msc,
                                               const int* __restrict__ cls,
                                               const unsigned* __restrict__ hist,
                                               float* __restrict__ det,
                                               float* __restrict__ offb,
                                               unsigned* __restrict__ valid) {
#pragma clang fp contract(off)
    __shared__ u64 keys[CAP];
    __shared__ int sB;
    __shared__ unsigned lcnt;
    const int b = blockIdx.x, t = threadIdx.x;
    const float* ms = msc + (size_t)b * NPRED;

    if (t == 0) lcnt = 0;
    if (t < 64) {  // wave 0: suffix-count boundary bin B
        const int lane = t;
        const unsigned* h = hist + b * NBINS;
        const int hi2 = 1024 - 16 * lane;       // lane chunk: bins [hi2-15, hi2]
        unsigned sum = 0;
        for (int k = 0; k < 16; ++k) sum += h[hi2 - k];
        if (lane == 63) sum += h[0];
        unsigned v = sum;
        for (int d = 1; d < 64; d <<= 1) {
            unsigned o = __shfl_up(v, d);
            if (lane >= d) v += o;
        }
        unsigned excl = v - sum;                // count strictly above my chunk
        u64 ball = __ballot(v >= NTOP);
        int B = 0;
        if (ball != 0) {
            int sel = __builtin_ctzll(ball);
            if (lane == sel) {
                unsigned run = excl;
                for (int k = 0; k < 16; ++k) {
                    run += h[hi2 - k];
                    if (run >= NTOP) { B = hi2 - k; break; }
                }
            }
            B = __shfl(B, sel);
        }
        if (lane == 0) sB = B;
    }
    __syncthreads();
    const int B = sB;

    // compact candidates (bin >= B) into LDS
    for (int p = t; p < NPRED; p += 1024) {
        float s = ms[p];
        if (s > CONF_T) {
            unsigned bits = __float_as_uint(s);
            int bin = (int)(bits >> 14) - 0xFA00;
            bin = bin < 0 ? 0 : (bin > 1024 ? 1024 : bin);
            if (bin >= B) {
                unsigned slot = atomicAdd(&lcnt, 1u);
                if (slot < CAP)
                    keys[slot] = ((u64)(~bits) << 32) | (unsigned)p;
            }
        }
    }
    __syncthreads();
    unsigned c = lcnt; if (c > CAP) c = CAP;
    for (int i = (int)c + t; i < CAP; i += 1024) keys[i] = ~0ULL;
    __syncthreads();

    // ---- hybrid bitonic sort, CAP=2048 keys ascending ----
    const unsigned ia = (((unsigned)t & ~63u) << 1) | ((unsigned)t & 63u);
    const unsigned ib = ia + 64u;

    // register compare-exchange with intra-wave partner (j <= 32)
    auto ce = [&](u64& v, unsigned i, unsigned j, unsigned k) {
        u64 pv = shfl_xor_u64(v, (int)j);
        bool asc = ((i & k) == 0u);
        bool lower = ((i & j) == 0u);
        bool takeMin = (asc == lower);
        bool less = (v < pv);
        v = (takeMin == less) ? v : pv;
    };

    // phase 1: k = 2..64 entirely in registers (partners within 64-segment)
    {
        u64 a = keys[ia], d = keys[ib];
        for (unsigned k = 2; k <= 64; k <<= 1)
            for (unsigned j = k >> 1; j >= 1; j >>= 1) {
                ce(a, ia, j, k);
                ce(d, ib, j, k);
            }
        keys[ia] = a; keys[ib] = d;
    }
    __syncthreads();

    // phase 2: k = 128..2048; j>=64 in LDS, j<=32 in registers
    for (unsigned k = 128; k <= CAP; k <<= 1) {
        for (unsigned j = k >> 1; j >= 64; j >>= 1) {
            unsigned i = (((unsigned)t & ~(j - 1)) << 1) | ((unsigned)t & (j - 1));
            unsigned pi = i | j;
            bool up = ((i & k) == 0);
            u64 a = keys[i], d = keys[pi];
            bool sw = up ? (a > d) : (a < d);
            if (sw) { keys[i] = d; keys[pi] = a; }
            __syncthreads();
        }
        u64 a = keys[ia], d = keys[ib];
        for (unsigned j = 32; j >= 1; j >>= 1) {
            ce(a, ia, j, k);
            ce(d, ib, j, k);
        }
        keys[ia] = a; keys[ib] = d;
        __syncthreads();
    }

    // gather top-1000 -> det rows, class-offset boxes, valid flags
    if (t < NTOP) {
        u64 key = keys[t];
        unsigned p = (unsigned)key;
        float score = __uint_as_float(~(unsigned)(key >> 32));
        bool v = score > CONF_T;
        float o0 = 0, o1 = 0, o2 = 0, o3 = 0, o4 = 0, o5 = 0;
        float f0 = 0, f1 = 0, f2 = 0, f3 = 0;
        if (v) {
            const float* xp = x + ((size_t)b * NPRED + p) * 85;
            float xc = xp[0], yc = xp[1], w = xp[2], h = xp[3];
            float hw = w * 0.5f, hh = h * 0.5f;
            o0 = xc - hw; o1 = yc - hh; o2 = xc + hw; o3 = yc + hh;
            o4 = score;
            float cf = (float)cls[(size_t)b * NPRED + p];
            o5 = cf;
            float co = cf * MAXWH;
            f0 = o0 + co; f1 = o1 + co; f2 = o2 + co; f3 = o3 + co;
        }
        size_t d6 = ((size_t)b * NTOP + t) * 6;
        det[d6 + 0] = o0; det[d6 + 1] = o1; det[d6 + 2] = o2;
        det[d6 + 3] = o3; det[d6 + 4] = o4; det[d6 + 5] = o5;
        size_t d4 = ((size_t)b * NTOP + t) * 4;
        offb[d4 + 0] = f0; offb[d4 + 1] = f1; offb[d4 + 2] = f2; offb[d4 + 3] = f3;
        valid[(size_t)b * NTOP + t] = v ? 1u : 0u;
    }
}

// ---------------------------------------------------------------------------
// K3: 1000x1000 IoU bitmask. Lanes <-> consecutive rows; columns are
// broadcast LDS reads (conflict-free). grid = 8 batches x 32 row-groups.
// ---------------------------------------------------------------------------
__global__ __launch_bounds__(256) void k_iou(const float* __restrict__ offb,
                                             u64* __restrict__ mask) {
#pragma clang fp contract(off)
    __shared__ __align__(16) float4 bx4[NTOP];
    __shared__ float area[NTOP];
    const int b = blockIdx.x >> 5;
    const int rg = blockIdx.x & 31;
    const float4* ob = (const float4*)(offb + (size_t)b * NTOP * 4);
    for (int i = threadIdx.x; i < NTOP; i += 256) {
        float4 v = ob[i];
        bx4[i] = v;
        area[i] = (v.z - v.x) * (v.w - v.y);
    }
    __syncthreads();
    const int i = rg * 32 + (threadIdx.x & 31);
    const int q = threadIdx.x >> 5;            // 8 word-pairs
    if (i >= NTOP) return;
    float4 A = bx4[i];
    float areaA = area[i];
    u64* mrow = &mask[((size_t)b * NTOP + i) * 16];
    for (int wi = 0; wi < 2; ++wi) {
        int w = q * 2 + wi;
        u64 bits = 0;
        int c0 = w * 64;
        for (int cc = 0; cc < 64; ++cc) {
            int col = c0 + cc;
            if (col >= NTOP) break;
            float4 Bb = bx4[col];              // broadcast read
            float ltx = fmaxf(A.x, Bb.x), lty = fmaxf(A.y, Bb.y);
            float rbx = fminf(A.z, Bb.z), rby = fminf(A.w, Bb.w);
            float ww = fmaxf(rbx - ltx, 0.0f), hh = fmaxf(rby - lty, 0.0f);
            float inter = ww * hh;
            float iou = inter / (((areaA + area[col]) - inter) + 1e-9f);
            if (iou > IOU_THR && col != i) bits |= (1ULL << cc);
        }
        mrow[w] = bits;
    }
}

// ---------------------------------------------------------------------------
// K4: greedy scan, one wave per batch. Event-driven scalar formulation
// (see round-1 notes). __launch_bounds__(64, 1): this kernel runs 8 blocks
// of 1 wave each chip-wide; min-waves=1 unlocks the full 512-VGPR budget so
// acc[16]+vbs[16]+buf[3][16] (u64) live in registers instead of scratch
// (round-0 showed VGPR=72 + 187 KB of spill stores).
// ---------------------------------------------------------------------------
__global__ __launch_bounds__(64, 1) void k_scan(const u64* __restrict__ mask,
                                                const unsigned* __restrict__ valid,
                                                const float* __restrict__ det,
                                                float* __restrict__ out) {
    const int b = blockIdx.x;
    const int lane = threadIdx.x;
    const u64* mb = mask + (size_t)b * NTOP * 16;
    u64 acc[16];
    u64 buf[3][16];
#pragma unroll
    for (int w = 0; w < 16; ++w) acc[w] = 0;

    u64 vbs[16];
#pragma unroll
    for (int g = 0; g < 16; ++g) {
        int r = g * 64 + lane;
        unsigned vf = (r < NTOP) ? valid[(size_t)b * NTOP + r] : 0u;
        vbs[g] = __ballot(vf != 0);   // wave-uniform -> SGPRs
    }

    auto loadgrp = [&](int g, u64* dst) {
        int r = g * 64 + lane;
        if (r < NTOP) {
            const u64* rp = mb + (size_t)r * 16;
#pragma unroll
            for (int w = 0; w < 16; ++w) dst[w] = rp[w];
        } else {
#pragma unroll
            for (int w = 0; w < 16; ++w) dst[w] = 0;
        }
    };
    loadgrp(0, buf[0]);
    loadgrp(1, buf[1]);

#pragma unroll
    for (int g = 0; g < 16; ++g) {
        if (g + 2 < 16) loadgrp(g + 2, buf[(g + 2) % 3]);
        u64* cur = buf[g % 3];

        // wave-uniform suppression word for this group from prior keeps;
        // butterfly OR-reduce, then pin to SGPRs so the event loop is SALU.
        u64 Sv = acc[g];
        Sv |= shfl_xor_u64(Sv, 1);  Sv |= shfl_xor_u64(Sv, 2);  Sv |= shfl_xor_u64(Sv, 4);
        Sv |= shfl_xor_u64(Sv, 8);  Sv |= shfl_xor_u64(Sv, 16); Sv |= shfl_xor_u64(Sv, 32);
        unsigned slo = (unsigned)__builtin_amdgcn_readfirstlane((int)(unsigned)Sv);
        unsigned shi = (unsigned)__builtin_amdgcn_readfirstlane((int)(unsigned)(Sv >> 32));
        u64 S = ((u64)shi << 32) | slo;

        const u64 vb = vbs[g];
        const u64 nz = __ballot(cur[g] != 0ULL);   // rows with intra-group bits
        const int clo = (int)(unsigned)cur[g];
        const int chi = (int)(unsigned)(cur[g] >> 32);

        u64 kb = 0;
        u64 events = nz & vb & ~S;   // kept-candidates that can change S
        while (events) {
            int t = (int)__builtin_ctzll(events);
            u64 bit = 1ULL << t;
            u64 below = bit - 1;
            kb |= vb & ~S & below;   // finalize zero-row span below this event
            kb |= bit;               // event row is valid & unsuppressed: keep
            unsigned mlo = (unsigned)__builtin_amdgcn_readlane(clo, t);
            unsigned mhi = (unsigned)__builtin_amdgcn_readlane(chi, t);
            S |= ((u64)mhi << 32) | mlo;
            events &= ~bit;
            events &= ~S;
        }
        kb |= vb & ~S;               // finalize remainder under final S

        bool mykeep = (kb >> lane) & 1ULL;
#pragma unroll
        for (int w = 0; w < 16; ++w) acc[w] |= mykeep ? cur[w] : 0ULL;

        int r = g * 64 + lane;          // fused masked output write
        if (r < NTOP) {
            const float* dp = det + ((size_t)b * NTOP + r) * 6;
            float* op = out + ((size_t)b * NTOP + r) * 6;
#pragma unroll
            for (int c2 = 0; c2 < 6; ++c2) {
                float v = dp[c2];
                op[c2] = mykeep ? v : 0.0f;
            }
        }
    }
}

// ---------------------------------------------------------------------------
extern "C" void kernel_launch(void* const* d_in, const int* in_sizes, int n_in,
                              void* d_out, int out_size, void* d_ws, size_t ws_size,
                              hipStream_t stream) {
    const float* x = (const float*)d_in[0];
    char* ws = (char*)d_ws;
    // layout (bytes):
    float* msc = (float*)(ws);                       //       0 .. 806400
    int* cls = (int*)(ws + 806400);                  //  806400 .. 1612800
    float* det = (float*)(ws + 1612800);             // 1612800 .. 1804800
    float* offb = (float*)(ws + 1804800);            // 1804800 .. 1932800
    unsigned* valid = (unsigned*)(ws + 1932800);     // 1932800 .. 1964800
    u64* mask = (u64*)(ws + 1964800);                // 1964800 .. 2988800
    // hist overlays the mask region (consumed by k_sort before k_iou writes):
    unsigned* hist = (unsigned*)(ws + 1964800);      // 8*1025*4 = 32800

    hipMemsetAsync(hist, 0, 32800, stream);
    k_score<<<NB * SBPB, 128, 0, stream>>>(x, msc, cls, hist);
    k_sort<<<NB, 1024, 0, stream>>>(x, msc, cls, hist, det, offb, valid);
    k_iou<<<NB * 32, 256, 0, stream>>>(offb, mask);
    k_scan<<<NB, 64, 0, stream>>>(mask, valid, det, (float*)d_out);
}

// Round 3
// 167.267 us; speedup vs baseline: 1.3092x; 1.0384x over previous
//
#include <hip/hip_runtime.h>
#include <stdint.h>

#define NB 8
#define NPRED 25200
#define NTOP 1000
#define NCLS 80
#define CONF_T 0.25f
#define IOU_THR 0.45f
#define MAXWH 4096.0f
#define CAP 2048
#define NBINS 1025
#define SBLK 128
#define SBPB 197   // ceil(25200/128): 197*128 = 25216

typedef unsigned long long u64;

__device__ __forceinline__ u64 shfl_xor_u64(u64 v, int m) {
    int lo = __shfl_xor((int)(unsigned)v, m);
    int hi = __shfl_xor((int)(unsigned)(v >> 32), m);
    return ((u64)(unsigned)hi << 32) | (unsigned)lo;
}

// ---------------------------------------------------------------------------
// K1: score/class per pred. 256 threads / 128 preds: thread pair (t>>1, t&1)
// splits the 80-class argmax 40/40, combined with one __shfl_xor (partner
// t^1 is same-wave). 12 waves/CU (vs 6) for latency hiding; compute phase
// halved. Global histogram REMOVED (k_sort builds it in LDS) -> no global
// atomics here and no separate memset dispatch.
// Staging via global_load_lds width=16 (no VGPR round trip).
// ---------------------------------------------------------------------------
__global__ __launch_bounds__(256) void k_score(const float* __restrict__ x,
                                               float* __restrict__ msc,
                                               int* __restrict__ cls) {
#pragma clang fp contract(off)
    __shared__ __align__(16) float sm[SBLK * 85];
    const int b = blockIdx.x / SBPB;
    const int blk = blockIdx.x % SBPB;
    const int t = threadIdx.x;
    const int wave = t >> 6, lane = t & 63;
    const long long TOT4 = (long long)NB * NPRED * 85 / 4;  // 4,284,000
    const long long base4 = ((long long)b * NPRED + (long long)blk * SBLK) * 85 / 4;
    const float4* x4 = (const float4*)x;
    const int tile4 = SBLK * 85 / 4;  // 2720

    for (int k = 0; k < 11; ++k) {
        int ib = k * 256 + wave * 64;      // wave-uniform lds base (float4 units)
        int fi = ib + lane;
        if (fi < tile4) {
            long long gi = base4 + fi;
            if (gi >= TOT4) gi = TOT4 - 1;  // tail clamp (outputs guarded below)
            __builtin_amdgcn_global_load_lds(
                (const __attribute__((address_space(1))) void*)(x4 + gi),
                (__attribute__((address_space(3))) void*)(sm + (size_t)ib * 4),
                16, 0, 0);
        }
    }
    __syncthreads();

    const int p = t >> 1;        // pred within block [0,128)
    const int h = t & 1;         // class-half: 0 -> classes 0..39, 1 -> 40..79
    const int pred = blk * SBLK + p;
    const float* rowp = &sm[p * 85];
    // bank note: lane->addr stride 85 floats (gcd(21,32)=1) and the odd-half
    // +40 offset alias 2-way at most -> conflict-free (2 lanes/bank is free).
    float obj = rowp[4];
    const int cb = 5 + h * 40;
    float best = rowp[cb];
    int bid = h * 40;
    for (int c = 1; c < 40; ++c) {
        float v = rowp[cb + c];
        if (v > best) { best = v; bid = h * 40 + c; }  // strict >: first occurrence
    }
    float obest = __shfl_xor(best, 1);
    int obid = __shfl_xor(bid, 1);
    if (h == 0 && pred < NPRED) {
        float fb = best; int fc = bid;
        if (obest > fb) { fb = obest; fc = obid; }  // ties -> lower class idx (h=0)
        float score = obj * fb;
        int q = b * NPRED + pred;
        msc[q] = (score > CONF_T) ? score : -1.0f;
        cls[q] = fc;
    }
}

// ---------------------------------------------------------------------------
// K2 (fused): per-batch LDS histogram (pass A) + boundary-bin + compaction
// (pass B) + hybrid bitonic sort of <=2048 candidates + gather top-1000.
// Key = (~score_bits << 32) | idx : ascending sort = descending score,
// ascending index on ties (stable top_k semantics).
// Bitonic: j>=64 levels in LDS (consecutive-lane u64 = 2 lanes/bank, free);
// j<=32 levels in registers via __shfl_xor; k=2..64 fused, no barriers.
// ---------------------------------------------------------------------------
__global__ __launch_bounds__(1024) void k_sort(const float* __restrict__ x,
                                               const float* __restrict__ msc,
                                               const int* __restrict__ cls,
                                               float* __restrict__ det,
                                               float* __restrict__ offb,
                                               unsigned* __restrict__ valid) {
#pragma clang fp contract(off)
    __shared__ u64 keys[CAP];
    __shared__ unsigned hh[NBINS];
    __shared__ int sB;
    __shared__ unsigned lcnt;
    const int b = blockIdx.x, t = threadIdx.x;
    const float* ms = msc + (size_t)b * NPRED;

    for (int i = t; i < NBINS; i += 1024) hh[i] = 0;
    if (t == 0) lcnt = 0;
    __syncthreads();

    // pass A: per-batch histogram of score bits (LDS atomics)
    for (int p = t; p < NPRED; p += 1024) {
        float s = ms[p];
        if (s > CONF_T) {
            unsigned bits = __float_as_uint(s);
            int bin = (int)(bits >> 14) - 0xFA00;
            bin = bin < 0 ? 0 : (bin > 1024 ? 1024 : bin);
            atomicAdd(&hh[bin], 1u);
        }
    }
    __syncthreads();

    if (t < 64) {  // wave 0: suffix-count boundary bin B
        const int lane = t;
        const int hi2 = 1024 - 16 * lane;       // lane chunk: bins [hi2-15, hi2]
        unsigned sum = 0;
        for (int k = 0; k < 16; ++k) sum += hh[hi2 - k];
        if (lane == 63) sum += hh[0];
        unsigned v = sum;
        for (int d = 1; d < 64; d <<= 1) {
            unsigned o = __shfl_up(v, d);
            if (lane >= d) v += o;
        }
        unsigned excl = v - sum;                // count strictly above my chunk
        u64 ball = __ballot(v >= NTOP);
        int B = 0;
        if (ball != 0) {
            int sel = __builtin_ctzll(ball);
            if (lane == sel) {
                unsigned run = excl;
                for (int k = 0; k < 16; ++k) {
                    run += hh[hi2 - k];
                    if (run >= NTOP) { B = hi2 - k; break; }
                }
            }
            B = __shfl(B, sel);
        }
        if (lane == 0) sB = B;
    }
    __syncthreads();
    const int B = sB;

    // pass B: compact candidates (bin >= B) into LDS (msc is L2-hot now)
    for (int p = t; p < NPRED; p += 1024) {
        float s = ms[p];
        if (s > CONF_T) {
            unsigned bits = __float_as_uint(s);
            int bin = (int)(bits >> 14) - 0xFA00;
            bin = bin < 0 ? 0 : (bin > 1024 ? 1024 : bin);
            if (bin >= B) {
                unsigned slot = atomicAdd(&lcnt, 1u);
                if (slot < CAP)
                    keys[slot] = ((u64)(~bits) << 32) | (unsigned)p;
            }
        }
    }
    __syncthreads();
    unsigned c = lcnt; if (c > CAP) c = CAP;
    for (int i = (int)c + t; i < CAP; i += 1024) keys[i] = ~0ULL;
    __syncthreads();

    // ---- hybrid bitonic sort, CAP=2048 keys ascending ----
    const unsigned ia = (((unsigned)t & ~63u) << 1) | ((unsigned)t & 63u);
    const unsigned ib = ia + 64u;

    auto ce = [&](u64& v, unsigned i, unsigned j, unsigned k) {
        u64 pv = shfl_xor_u64(v, (int)j);
        bool asc = ((i & k) == 0u);
        bool lower = ((i & j) == 0u);
        bool takeMin = (asc == lower);
        bool less = (v < pv);
        v = (takeMin == less) ? v : pv;
    };

    // phase 1: k = 2..64 entirely in registers (partners within 64-segment)
    {
        u64 a = keys[ia], d = keys[ib];
        for (unsigned k = 2; k <= 64; k <<= 1)
            for (unsigned j = k >> 1; j >= 1; j >>= 1) {
                ce(a, ia, j, k);
                ce(d, ib, j, k);
            }
        keys[ia] = a; keys[ib] = d;
    }
    __syncthreads();

    // phase 2: k = 128..2048; j>=64 in LDS, j<=32 in registers
    for (unsigned k = 128; k <= CAP; k <<= 1) {
        for (unsigned j = k >> 1; j >= 64; j >>= 1) {
            unsigned i = (((unsigned)t & ~(j - 1)) << 1) | ((unsigned)t & (j - 1));
            unsigned pi = i | j;
            bool up = ((i & k) == 0);
            u64 a = keys[i], d = keys[pi];
            bool sw = up ? (a > d) : (a < d);
            if (sw) { keys[i] = d; keys[pi] = a; }
            __syncthreads();
        }
        u64 a = keys[ia], d = keys[ib];
        for (unsigned j = 32; j >= 1; j >>= 1) {
            ce(a, ia, j, k);
            ce(d, ib, j, k);
        }
        keys[ia] = a; keys[ib] = d;
        __syncthreads();
    }

    // gather top-1000 -> det rows, class-offset boxes, valid flags
    if (t < NTOP) {
        u64 key = keys[t];
        unsigned p = (unsigned)key;
        float score = __uint_as_float(~(unsigned)(key >> 32));
        bool v = score > CONF_T;
        float o0 = 0, o1 = 0, o2 = 0, o3 = 0, o4 = 0, o5 = 0;
        float f0 = 0, f1 = 0, f2 = 0, f3 = 0;
        if (v) {
            const float* xp = x + ((size_t)b * NPRED + p) * 85;
            float xc = xp[0], yc = xp[1], w = xp[2], h = xp[3];
            float hw = w * 0.5f, hh2 = h * 0.5f;
            o0 = xc - hw; o1 = yc - hh2; o2 = xc + hw; o3 = yc + hh2;
            o4 = score;
            float cf = (float)cls[(size_t)b * NPRED + p];
            o5 = cf;
            float co = cf * MAXWH;
            f0 = o0 + co; f1 = o1 + co; f2 = o2 + co; f3 = o3 + co;
        }
        size_t d6 = ((size_t)b * NTOP + t) * 6;
        det[d6 + 0] = o0; det[d6 + 1] = o1; det[d6 + 2] = o2;
        det[d6 + 3] = o3; det[d6 + 4] = o4; det[d6 + 5] = o5;
        size_t d4 = ((size_t)b * NTOP + t) * 4;
        offb[d4 + 0] = f0; offb[d4 + 1] = f1; offb[d4 + 2] = f2; offb[d4 + 3] = f3;
        valid[(size_t)b * NTOP + t] = v ? 1u : 0u;
    }
}

// ---------------------------------------------------------------------------
// K3: 1000x1000 IoU bitmask. Lanes <-> consecutive rows; columns are
// broadcast LDS reads (conflict-free). grid = 8 batches x 32 row-groups.
// ---------------------------------------------------------------------------
__global__ __launch_bounds__(256) void k_iou(const float* __restrict__ offb,
                                             u64* __restrict__ mask) {
#pragma clang fp contract(off)
    __shared__ __align__(16) float4 bx4[NTOP];
    __shared__ float area[NTOP];
    const int b = blockIdx.x >> 5;
    const int rg = blockIdx.x & 31;
    const float4* ob = (const float4*)(offb + (size_t)b * NTOP * 4);
    for (int i = threadIdx.x; i < NTOP; i += 256) {
        float4 v = ob[i];
        bx4[i] = v;
        area[i] = (v.z - v.x) * (v.w - v.y);
    }
    __syncthreads();
    const int i = rg * 32 + (threadIdx.x & 31);
    const int q = threadIdx.x >> 5;            // 8 word-pairs
    if (i >= NTOP) return;
    float4 A = bx4[i];
    float areaA = area[i];
    u64* mrow = &mask[((size_t)b * NTOP + i) * 16];
    for (int wi = 0; wi < 2; ++wi) {
        int w = q * 2 + wi;
        u64 bits = 0;
        int c0 = w * 64;
        for (int cc = 0; cc < 64; ++cc) {
            int col = c0 + cc;
            if (col >= NTOP) break;
            float4 Bb = bx4[col];              // broadcast read
            float ltx = fmaxf(A.x, Bb.x), lty = fmaxf(A.y, Bb.y);
            float rbx = fminf(A.z, Bb.z), rby = fminf(A.w, Bb.w);
            float ww = fmaxf(rbx - ltx, 0.0f), hh = fmaxf(rby - lty, 0.0f);
            float inter = ww * hh;
            float iou = inter / (((areaA + area[col]) - inter) + 1e-9f);
            if (iou > IOU_THR && col != i) bits |= (1ULL << cc);
        }
        mrow[w] = bits;
    }
}

// ---------------------------------------------------------------------------
// K4: greedy scan, one wave per batch. Event-driven scalar formulation
// (round-1 notes). (64,1) unlocks full VGPR budget; mask rows loaded as
// ulonglong2 (16B) to halve issue count on the latency-bound prefetch.
// ---------------------------------------------------------------------------
__global__ __launch_bounds__(64, 1) void k_scan(const u64* __restrict__ mask,
                                                const unsigned* __restrict__ valid,
                                                const float* __restrict__ det,
                                                float* __restrict__ out) {
    const int b = blockIdx.x;
    const int lane = threadIdx.x;
    const u64* mb = mask + (size_t)b * NTOP * 16;
    u64 acc[16];
    u64 buf[3][16];
#pragma unroll
    for (int w = 0; w < 16; ++w) acc[w] = 0;

    u64 vbs[16];
#pragma unroll
    for (int g = 0; g < 16; ++g) {
        int r = g * 64 + lane;
        unsigned vf = (r < NTOP) ? valid[(size_t)b * NTOP + r] : 0u;
        vbs[g] = __ballot(vf != 0);   // wave-uniform -> SGPRs
    }

    auto loadgrp = [&](int g, u64* dst) {
        int r = g * 64 + lane;
        if (r < NTOP) {
            const ulonglong2* rp = (const ulonglong2*)(mb + (size_t)r * 16);
#pragma unroll
            for (int w = 0; w < 8; ++w) {
                ulonglong2 v = rp[w];
                dst[2 * w] = v.x; dst[2 * w + 1] = v.y;
            }
        } else {
#pragma unroll
            for (int w = 0; w < 16; ++w) dst[w] = 0;
        }
    };
    loadgrp(0, buf[0]);
    loadgrp(1, buf[1]);

#pragma unroll
    for (int g = 0; g < 16; ++g) {
        if (g + 2 < 16) loadgrp(g + 2, buf[(g + 2) % 3]);
        u64* cur = buf[g % 3];

        // wave-uniform suppression word for this group from prior keeps;
        // butterfly OR-reduce, then pin to SGPRs so the event loop is SALU.
        u64 Sv = acc[g];
        Sv |= shfl_xor_u64(Sv, 1);  Sv |= shfl_xor_u64(Sv, 2);  Sv |= shfl_xor_u64(Sv, 4);
        Sv |= shfl_xor_u64(Sv, 8);  Sv |= shfl_xor_u64(Sv, 16); Sv |= shfl_xor_u64(Sv, 32);
        unsigned slo = (unsigned)__builtin_amdgcn_readfirstlane((int)(unsigned)Sv);
        unsigned shi = (unsigned)__builtin_amdgcn_readfirstlane((int)(unsigned)(Sv >> 32));
        u64 S = ((u64)shi << 32) | slo;

        const u64 vb = vbs[g];
        const u64 nz = __ballot(cur[g] != 0ULL);   // rows with intra-group bits
        const int clo = (int)(unsigned)cur[g];
        const int chi = (int)(unsigned)(cur[g] >> 32);

        u64 kb = 0;
        u64 events = nz & vb & ~S;   // kept-candidates that can change S
        while (events) {
            int t = (int)__builtin_ctzll(events);
            u64 bit = 1ULL << t;
            u64 below = bit - 1;
            kb |= vb & ~S & below;   // finalize zero-row span below this event
            kb |= bit;               // event row is valid & unsuppressed: keep
            unsigned mlo = (unsigned)__builtin_amdgcn_readlane(clo, t);
            unsigned mhi = (unsigned)__builtin_amdgcn_readlane(chi, t);
            S |= ((u64)mhi << 32) | mlo;
            events &= ~bit;
            events &= ~S;
        }
        kb |= vb & ~S;               // finalize remainder under final S

        bool mykeep = (kb >> lane) & 1ULL;
#pragma unroll
        for (int w = 0; w < 16; ++w) acc[w] |= mykeep ? cur[w] : 0ULL;

        int r = g * 64 + lane;          // fused masked output write
        if (r < NTOP) {
            const float* dp = det + ((size_t)b * NTOP + r) * 6;
            float* op = out + ((size_t)b * NTOP + r) * 6;
#pragma unroll
            for (int c2 = 0; c2 < 6; ++c2) {
                float v = dp[c2];
                op[c2] = mykeep ? v : 0.0f;
            }
        }
    }
}

// ---------------------------------------------------------------------------
extern "C" void kernel_launch(void* const* d_in, const int* in_sizes, int n_in,
                              void* d_out, int out_size, void* d_ws, size_t ws_size,
                              hipStream_t stream) {
    const float* x = (const float*)d_in[0];
    char* ws = (char*)d_ws;
    // layout (bytes):
    float* msc = (float*)(ws);                       //       0 .. 806400
    int* cls = (int*)(ws + 806400);                  //  806400 .. 1612800
    float* det = (float*)(ws + 1612800);             // 1612800 .. 1804800
    float* offb = (float*)(ws + 1804800);            // 1804800 .. 1932800
    unsigned* valid = (unsigned*)(ws + 1932800);     // 1932800 .. 1964800
    u64* mask = (u64*)(ws + 1964800);                // 1964800 .. 2988800

    k_score<<<NB * SBPB, 256, 0, stream>>>(x, msc, cls);
    k_sort<<<NB, 1024, 0, stream>>>(x, msc, cls, det, offb, valid);
    k_iou<<<NB * 32, 256, 0, stream>>>(offb, mask);
    k_scan<<<NB, 64, 0, stream>>>(mask, valid, det, (float*)d_out);
}